// Round 6
// baseline (682.572 us; speedup 1.0000x reference)
//
#include <hip/hip_runtime.h>

#define SEQ_LEN 96
#define PRED_LEN 16
#define HIDDEN 64
#define FEAT 7
#define BATCH 512
#define TL (SEQ_LEN + PRED_LEN)   // 112-row sliding timeline
#define XSTR 8                    // padded row stride; col 7 == 1.0 (bias lane)

typedef float v2f __attribute__((ext_vector_type(2)));

#define L2E 1.4426950408889634f

// DPP quad ops (pure VALU). Quad = the 4 lanes of one hidden unit.
__device__ __forceinline__ float qp_xor1(float v) {  // [1,0,3,2]
    return __int_as_float(__builtin_amdgcn_mov_dpp(__float_as_int(v), 0xB1, 0xF, 0xF, true));
}
__device__ __forceinline__ float qp_xor2(float v) {  // [2,3,0,1]
    return __int_as_float(__builtin_amdgcn_mov_dpp(__float_as_int(v), 0x4E, 0xF, 0xF, true));
}
__device__ __forceinline__ float qp_rot1(float v) {  // lane q <- lane (q+1)&3 : [1,2,3,0]
    return __int_as_float(__builtin_amdgcn_mov_dpp(__float_as_int(v), 0x39, 0xF, 0xF, true));
}
__device__ __forceinline__ float qp_rot3(float v) {  // lane q <- lane (q+3)&3 : [3,0,1,2]
    return __int_as_float(__builtin_amdgcn_mov_dpp(__float_as_int(v), 0x93, 0xF, 0xF, true));
}

// Forced packed fp32 math (r13; proven neutral-at-worst, keeps packing honest).
__device__ __forceinline__ v2f pk_mul(v2f a, v2f b) {
    v2f d;
    asm("v_pk_mul_f32 %0, %1, %2" : "=v"(d) : "v"(a), "v"(b));
    return d;
}
__device__ __forceinline__ void pk_fma(v2f& acc, v2f a, v2f b) {
    asm("v_pk_fma_f32 %0, %1, %2, %0" : "+v"(acc) : "v"(a), "v"(b));
}

struct VV { v2f a, b; };

// r15: ILP-2 pivot -- TWO batch elements per block, shared weights.
//  r7-r14 post-mortem: issue fixes, decomposition changes, and sync fixes all
//  pinned at the same wall. VALUBusy 62% of an 860cyc step = ~320 cyc where
//  BOTH resident waves stall together: the 2 co-resident blocks' periodic
//  barriers phase-lock in-phase, so cross-block TLP never fills the
//  h-read->FMA dependency shadow. Fix: put the second, INDEPENDENT chain in
//  the SAME wave (ILP, guaranteed) instead of another block (TLP, lucky).
//  - block = 256 thr = 2 batch elems; lane = r11 (unit u, K-quarter q) role
//    running two chains; weights SHARED (72 floats multiply both h vectors).
//  - grid 256 -> 1 block/CU, 1 wave/SIMD -> waves_per_eu(1,1) = 512-reg
//    budget/wave. True pressure ~140 << 512: removes the occupancy-driven
//    allocator cap behind every previous remat failure (64-132 VGPR).
//  - Success signal: VGPR_Count > 120. Wall model: issue ~280cyc (2 elems),
//    LDS pipe ~480cyc/CU-step, chain ~370 -> ~450-520 cyc/step for 2 elems.
__global__ __launch_bounds__(256)
__attribute__((amdgpu_waves_per_eu(1, 1)))
void lstm_ar_kernel(
    const float* __restrict__ x,     // [B, 96, 7]
    const float* __restrict__ W_ih,  // [256, 7]
    const float* __restrict__ W_hh,  // [256, 64]
    const float* __restrict__ b_ih,  // [256]
    const float* __restrict__ b_hh,  // [256]
    const float* __restrict__ fc_W,  // [7, 64]
    const float* __restrict__ fc_b,  // [7]
    float* __restrict__ out)         // [B, 16, 7]
{
    __shared__ float xsA[TL * XSTR];  // sliding timelines, col7 = 1.0
    __shared__ float xsB[TL * XSTR];
    __shared__ float hA0[HIDDEN], hA1[HIDDEN];   // h ping-pong, elem A
    __shared__ float hB0[HIDDEN], hB1[HIDDEN];   // h ping-pong, elem B
    __shared__ float hscr[HIDDEN];    // garbage-h sink (never read)
    __shared__ float fcw[FEAT * HIDDEN];
    __shared__ float fcb[FEAT];

    const int tid = threadIdx.x;
    const int bA  = blockIdx.x * 2;
    const int bB  = bA + 1;
    const int u   = tid >> 2;         // hidden unit 0..63
    const int q   = tid & 3;          // K-quarter 0..3, also "own gate" id

    // ---- per-thread weights (SHARED by both elems): 4 gates x K-quarter ----
    // accumulator k holds gate (q+k)&3  (rotated layout for the DPP reduce)
    v2f wh[4][8];
    #pragma unroll
    for (int k = 0; k < 4; ++k) {
        const int gate = (q + k) & 3;
        const float* wr = W_hh + ((gate << 6) + u) * HIDDEN + (q << 4);
        #pragma unroll
        for (int j = 0; j < 8; ++j) wh[k][j] = *(const v2f*)(wr + 2 * j);
    }
    v2f wx[4];                        // x cols [2q, 2q+2); q==3 pairs col6 with bias
    #pragma unroll
    for (int k = 0; k < 4; ++k) {
        const int gate = (q + k) & 3;
        const int row  = (gate << 6) + u;
        const int c0 = (q << 1), c1 = c0 + 1;
        wx[k].x = W_ih[row * FEAT + c0];
        wx[k].y = (c1 < FEAT) ? W_ih[row * FEAT + c1]
                              : (b_ih[row] + b_hh[row]);   // pairs with xs col7==1.0
    }

    // activation constants: lane q activates gate q; gate 2 is tanh
    const float bk  = (q == 2) ? (-2.0f * L2E) : (-L2E);
    const float bm  = (q == 2) ? 2.0f : 1.0f;
    const float bbc = (q == 2) ? -1.0f : 0.0f;

    // h-write pointers: real for q==0; sink slots (u+16q)&63 keep each store
    // instruction at a 2-per-bank pattern
    float* const sink = hscr + ((u + (q << 4)) & 63);
    float* const waA1 = (q == 0) ? (hA1 + u) : sink;
    float* const waA0 = (q == 0) ? (hA0 + u) : sink;
    float* const waB1 = (q == 0) ? (hB1 + u) : sink;
    float* const waB0 = (q == 0) ? (hB0 + u) : sink;

    // per-lane h-read bases: K-quarter q => 4 float4s at hb + 16q
    const float4* const hA40 = (const float4*)(hA0 + (q << 4));
    const float4* const hA41 = (const float4*)(hA1 + (q << 4));
    const float4* const hB40 = (const float4*)(hB0 + (q << 4));
    const float4* const hB41 = (const float4*)(hB1 + (q << 4));
    const float* const xqA = xsA + (q << 1);   // this lane's 2 x-cols
    const float* const xqB = xsB + (q << 1);

    // ---- stage timelines / fc / init ----
    for (int i = tid; i < TL * XSTR; i += 256) {
        int r = i >> 3, f = i & 7;
        float vA = 1.0f, vB = 1.0f;                        // col 7 = bias input
        if (f < FEAT) {
            vA = (r < SEQ_LEN) ? x[bA * SEQ_LEN * FEAT + r * FEAT + f] : 0.0f;
            vB = (r < SEQ_LEN) ? x[bB * SEQ_LEN * FEAT + r * FEAT + f] : 0.0f;
        }
        xsA[i] = vA;
        xsB[i] = vB;
    }
    for (int i = tid; i < FEAT * HIDDEN; i += 256) fcw[i] = fc_W[i];
    if (tid < FEAT)   fcb[tid] = fc_b[tid];
    if (tid < HIDDEN) { hA0[tid] = 0.0f; hB0[tid] = 0.0f; }
    float cA = 0.0f, cB = 0.0f;       // real only in q==0 lanes; bounded garbage elsewhere
    __syncthreads();

    // One step, BOTH chains interleaved. Prefetches first (no deps), then the
    // two independent dot/reduce/act/c chains; the scheduler fills each
    // chain's dependency stalls with the other chain's instructions.
    auto step = [&](v2f xvA, v2f xvB, int nrow,
                    const float4* __restrict__ h4A, const float4* __restrict__ h4B,
                    float* __restrict__ wA, float* __restrict__ wB) -> VV {
        v2f nA = *(const v2f*)(xqA + nrow * XSTR);
        v2f nB = *(const v2f*)(xqB + nrow * XSTR);

        v2f A0 = pk_mul(wx[0], xvA);  v2f B0 = pk_mul(wx[0], xvB);
        v2f A1 = pk_mul(wx[1], xvA);  v2f B1 = pk_mul(wx[1], xvB);
        v2f A2 = pk_mul(wx[2], xvA);  v2f B2 = pk_mul(wx[2], xvB);
        v2f A3 = pk_mul(wx[3], xvA);  v2f B3 = pk_mul(wx[3], xvB);

        #pragma unroll
        for (int j = 0; j < 4; ++j) {                 // 16 h values each, 4x reuse
            float4 hvA = h4A[j];
            float4 hvB = h4B[j];
            v2f alo; alo.x = hvA.x; alo.y = hvA.y;
            v2f ahi; ahi.x = hvA.z; ahi.y = hvA.w;
            v2f blo; blo.x = hvB.x; blo.y = hvB.y;
            v2f bhi; bhi.x = hvB.z; bhi.y = hvB.w;
            pk_fma(A0, wh[0][2*j],   alo);  pk_fma(B0, wh[0][2*j],   blo);
            pk_fma(A1, wh[1][2*j],   alo);  pk_fma(B1, wh[1][2*j],   blo);
            pk_fma(A2, wh[2][2*j],   alo);  pk_fma(B2, wh[2][2*j],   blo);
            pk_fma(A3, wh[3][2*j],   alo);  pk_fma(B3, wh[3][2*j],   blo);
            pk_fma(A0, wh[0][2*j+1], ahi);  pk_fma(B0, wh[0][2*j+1], bhi);
            pk_fma(A1, wh[1][2*j+1], ahi);  pk_fma(B1, wh[1][2*j+1], bhi);
            pk_fma(A2, wh[2][2*j+1], ahi);  pk_fma(B2, wh[2][2*j+1], bhi);
            pk_fma(A3, wh[3][2*j+1], ahi);  pk_fma(B3, wh[3][2*j+1], bhi);
        }

        // horizontal + balanced rotation-reduce: lane q gathers gate q
        float a0 = A0.x + A0.y, b0 = B0.x + B0.y;
        float a1 = A1.x + A1.y, b1 = B1.x + B1.y;
        float a2 = A2.x + A2.y, b2 = B2.x + B2.y;
        float a3 = A3.x + A3.y, b3 = B3.x + B3.y;
        float sA = (a0 + qp_rot1(a3)) + (qp_xor2(a2) + qp_rot3(a1));
        float sB = (b0 + qp_rot1(b3)) + (qp_xor2(b2) + qp_rot3(b1));

        // activate own gate (q==2 -> tanh, else sigmoid)
        float eA  = __builtin_amdgcn_exp2f(sA * bk);
        float eB  = __builtin_amdgcn_exp2f(sB * bk);
        float rA  = __builtin_amdgcn_rcpf(1.0f + eA);
        float rB  = __builtin_amdgcn_rcpf(1.0f + eB);
        float aA  = fmaf(bm, rA, bbc);
        float aB  = fmaf(bm, rB, bbc);

        // quad share: lane 0 sees act=i, p1=f, p2=g, p3=o
        float pA1 = qp_xor1(aA);       float pB1 = qp_xor1(aB);
        float pA2 = qp_xor2(aA);       float pB2 = qp_xor2(aB);
        float pA3 = qp_xor2(pA1);      float pB3 = qp_xor2(pB1);

        cA = fmaf(pA1, cA, aA * pA2);  // c = f*c + i*g
        cB = fmaf(pB1, cB, aB * pB2);
        float e2A = __builtin_amdgcn_exp2f(cA * (-2.0f * L2E));
        float e2B = __builtin_amdgcn_exp2f(cB * (-2.0f * L2E));
        float rrA = __builtin_amdgcn_rcpf(1.0f + e2A);
        float rrB = __builtin_amdgcn_rcpf(1.0f + e2B);
        float thA = fmaf(2.0f, rrA, -1.0f);
        float thB = fmaf(2.0f, rrB, -1.0f);
        *wA = pA3 * thA;               // h = o*tanh(c); q!=0 -> sink
        *wB = pB3 * thB;

        __syncthreads();               // the ONLY barrier per step
        VV r; r.a = nA; r.b = nB;
        return r;
    };

    for (int k = 0; k < PRED_LEN; ++k) {
        v2f curA = *(const v2f*)(xqA + k * XSTR);     // row k (t=0)
        v2f curB = *(const v2f*)(xqB + k * XSTR);
        for (int t = 0; t < SEQ_LEN; t += 2) {
            VV r1 = step(curA, curB, k + t + 1, hA40, hB40, waA1, waB1);
            curA = r1.a; curB = r1.b;
            VV r2 = step(curA, curB, k + t + 2, hA41, hB41, waA0, waB0);
            curA = r2.a; curB = r2.b;   // t=94: prefetch row k+96 (stale, discarded)
        }
        // after 96 steps the latest h is in hA0 / hB0

        // ---- prediction heads: wave 0 lanes 0..6 -> A, wave 1 lanes 0..6 -> B
        const int w = tid >> 6, l = tid & 63;
        if (w < 2 && l < FEAT) {
            const float* hb = (w == 0) ? hA0 : hB0;
            float*      xst = (w == 0) ? xsA : xsB;
            const int   bb  = (w == 0) ? bA  : bB;
            float p0 = fcb[l], p1 = 0.0f, p2 = 0.0f, p3 = 0.0f;
            const float4* hh = (const float4*)hb;
            #pragma unroll
            for (int j = 0; j < 16; ++j) {
                float4 hv = hh[j];
                p0 = fmaf(fcw[l * HIDDEN + 4 * j + 0], hv.x, p0);
                p1 = fmaf(fcw[l * HIDDEN + 4 * j + 1], hv.y, p1);
                p2 = fmaf(fcw[l * HIDDEN + 4 * j + 2], hv.z, p2);
                p3 = fmaf(fcw[l * HIDDEN + 4 * j + 3], hv.w, p3);
            }
            float pred = (p0 + p1) + (p2 + p3);
            out[(bb * PRED_LEN + k) * FEAT + l] = pred;
            xst[(SEQ_LEN + k) * XSTR + l] = pred;     // append; col7 stays 1.0
        }
        __syncthreads();
    }
}

extern "C" void kernel_launch(void* const* d_in, const int* in_sizes, int n_in,
                              void* d_out, int out_size, void* d_ws, size_t ws_size,
                              hipStream_t stream) {
    const float* x    = (const float*)d_in[0];
    const float* W_ih = (const float*)d_in[1];
    const float* W_hh = (const float*)d_in[2];
    const float* b_ih = (const float*)d_in[3];
    const float* b_hh = (const float*)d_in[4];
    const float* fc_W = (const float*)d_in[5];
    const float* fc_b = (const float*)d_in[6];
    float* out = (float*)d_out;

    lstm_ar_kernel<<<BATCH / 2, 256, 0, stream>>>(x, W_ih, W_hh, b_ih, b_hh, fc_W, fc_b, out);
}

// Round 7
// 572.768 us; speedup vs baseline: 1.1917x; 1.1917x over previous
//
#include <hip/hip_runtime.h>

#define SEQ_LEN 96
#define PRED_LEN 16
#define HIDDEN 64
#define FEAT 7
#define BATCH 512
#define TL (SEQ_LEN + PRED_LEN)   // 112-row sliding timeline
#define XSTR 8                    // padded row stride; col 7 == 1.0 (bias lane)

typedef float v2f __attribute__((ext_vector_type(2)));

#define L2E 1.4426950408889634f

// DPP quad ops (pure VALU). Quad = the 4 lanes of one hidden unit.
__device__ __forceinline__ float qp_xor1(float v) {  // [1,0,3,2]
    return __int_as_float(__builtin_amdgcn_mov_dpp(__float_as_int(v), 0xB1, 0xF, 0xF, true));
}
__device__ __forceinline__ float qp_xor2(float v) {  // [2,3,0,1]
    return __int_as_float(__builtin_amdgcn_mov_dpp(__float_as_int(v), 0x4E, 0xF, 0xF, true));
}
__device__ __forceinline__ float qp_rot1(float v) {  // lane q <- lane (q+1)&3 : [1,2,3,0]
    return __int_as_float(__builtin_amdgcn_mov_dpp(__float_as_int(v), 0x39, 0xF, 0xF, true));
}
__device__ __forceinline__ float qp_rot3(float v) {  // lane q <- lane (q+3)&3 : [3,0,1,2]
    return __int_as_float(__builtin_amdgcn_mov_dpp(__float_as_int(v), 0x93, 0xF, 0xF, true));
}

// Forced packed fp32 math (register-only asm, schedulable).
__device__ __forceinline__ v2f pk_mul(v2f a, v2f b) {
    v2f d;
    asm("v_pk_mul_f32 %0, %1, %2" : "=v"(d) : "v"(a), "v"(b));
    return d;
}
__device__ __forceinline__ void pk_fma(v2f& acc, v2f a, v2f b) {
    asm("v_pk_fma_f32 %0, %1, %2, %0" : "+v"(acc) : "v"(a), "v"(b));
}

// r16: de-fat the proven-best config.
//  r13/r15 cross-analysis: busy/SIMD/step ~535-545 cyc in BOTH (2 waves x 1
//  chain vs 1 wave x 2 chains) -> busy == real issue == ~135 insts/chain vs
//  ~62 semantic ops. ~70 insts/chain of structural fat: float4->v2f unpack
//  movs (b128 dest hi-half is odd-aligned -> copies for VOP3P operands),
//  lambda-boundary reg shuffles, per-call nrow*XSTR math, DPP-hazard nops.
//  Also: TLP-2 (r13, 430 cyc/chain) hides stalls better than in-wave ILP-2
//  (r15, 533) -> keep 2 staggered blocks/CU.
//  Changes vs r13:
//   1. no lambda: macro-inlined step bodies, ping-pong unrolled.
//   2. v2f LDS reads (8x ds_read_b64; every dest an even-aligned pair ->
//      zero unpack movs feeding the pk asm).
//   3. pointer-increment x addressing: px += XSTR, one v_add/step.
//   4. v2f-TUPLE asm anchors on the weights (r12's scalar anchors broke
//      packing; "+v" on the vector ties an aligned 64-bit tuple) to push the
//      allocator past its 88-reg choice under waves_per_eu(2,2).
//  Decomposition unchanged (r11, numerics proven): thread = (unit u, quarter
//  q); rotation-reduce; DPP share; redundant c-chain; 2-way sink stores.
__global__ __launch_bounds__(256)
__attribute__((amdgpu_waves_per_eu(2, 2)))
void lstm_ar_kernel(
    const float* __restrict__ x,     // [B, 96, 7]
    const float* __restrict__ W_ih,  // [256, 7]
    const float* __restrict__ W_hh,  // [256, 64]
    const float* __restrict__ b_ih,  // [256]
    const float* __restrict__ b_hh,  // [256]
    const float* __restrict__ fc_W,  // [7, 64]
    const float* __restrict__ fc_b,  // [7]
    float* __restrict__ out)         // [B, 16, 7]
{
    __shared__ float xs[TL * XSTR];   // sliding timeline, col7 = 1.0
    __shared__ float hb0[HIDDEN];     // h ping-pong
    __shared__ float hb1[HIDDEN];
    __shared__ float hscr[HIDDEN];    // garbage-h sink (never read)
    __shared__ float fcw[FEAT * HIDDEN];
    __shared__ float fcb[FEAT];

    const int tid = threadIdx.x;
    const int b   = blockIdx.x;
    const int u   = tid >> 2;         // hidden unit 0..63
    const int q   = tid & 3;          // K-quarter 0..3, also "own gate" id

    // ---- per-thread weights: 4 gates x K-quarter [16q,16q+16) ----
    // accumulator k holds gate (q+k)&3  (rotated layout for the DPP reduce)
    v2f wh[4][8];
    #pragma unroll
    for (int k = 0; k < 4; ++k) {
        const int gate = (q + k) & 3;
        const float* wr = W_hh + ((gate << 6) + u) * HIDDEN + (q << 4);
        #pragma unroll
        for (int j = 0; j < 8; ++j) wh[k][j] = *(const v2f*)(wr + 2 * j);
    }
    v2f wx[4];                        // x cols [2q, 2q+2); q==3 pairs col6 with bias
    #pragma unroll
    for (int k = 0; k < 4; ++k) {
        const int gate = (q + k) & 3;
        const int row  = (gate << 6) + u;
        const int c0 = (q << 1), c1 = c0 + 1;
        wx[k].x = W_ih[row * FEAT + c0];
        wx[k].y = (c1 < FEAT) ? W_ih[row * FEAT + c1]
                              : (b_ih[row] + b_hh[row]);   // pairs with xs col7==1.0
    }

    // ---- tuple anchors: pin each v2f weight pair in arch VGPRs, packed ----
    #pragma unroll
    for (int k = 0; k < 4; ++k) {
        #pragma unroll
        for (int j = 0; j < 8; ++j) asm volatile("" : "+v"(wh[k][j]));
        asm volatile("" : "+v"(wx[k]));
    }

    // activation constants: lane q activates gate q; gate 2 is tanh
    const float bk  = (q == 2) ? (-2.0f * L2E) : (-L2E);
    const float bm  = (q == 2) ? 2.0f : 1.0f;
    const float bbc = (q == 2) ? -1.0f : 0.0f;

    // pointers (all fixed for the whole kernel; ds offsets fold to immediates)
    const v2f* const hp0 = (const v2f*)(hb0 + (q << 4));
    const v2f* const hp1 = (const v2f*)(hb1 + (q << 4));
    float* const sink = hscr + ((u + (q << 4)) & 63);
    float* const wa1 = (q == 0) ? (hb1 + u) : sink;
    float* const wa0 = (q == 0) ? (hb0 + u) : sink;
    const float* const xq = xs + (q << 1);   // this lane's 2 x-cols

    // ---- stage timeline / fc / init ----
    for (int i = tid; i < TL * XSTR; i += 256) {
        int r = i >> 3, f = i & 7;
        float v = 1.0f;                                    // col 7 = bias input
        if (f < FEAT) v = (r < SEQ_LEN) ? x[b * SEQ_LEN * FEAT + r * FEAT + f] : 0.0f;
        xs[i] = v;
    }
    for (int i = tid; i < FEAT * HIDDEN; i += 256) fcw[i] = fc_W[i];
    if (tid < FEAT)   fcb[tid] = fc_b[tid];
    if (tid < HIDDEN) hb0[tid] = 0.0f;
    float c = 0.0f;                   // real only in q==0 lanes; bounded garbage elsewhere
    __syncthreads();

// One step, fully inlined. HP = h-read base (v2f*), WA = h-write ptr.
// 9 LDS reads (1 x, 8 h) issue up front; 36 pk ops; rotation-reduce; act;
// DPP share; c/tanh; write; px advance; ONE barrier.
#define STEP(HP, WA) {                                                        \
    v2f xv = *(const v2f*)px;                                                 \
    v2f h0 = (HP)[0], h1 = (HP)[1], h2 = (HP)[2], h3 = (HP)[3];               \
    v2f h4 = (HP)[4], h5 = (HP)[5], h6 = (HP)[6], h7 = (HP)[7];               \
    v2f A0 = pk_mul(wx[0], xv);                                               \
    v2f A1 = pk_mul(wx[1], xv);                                               \
    v2f A2 = pk_mul(wx[2], xv);                                               \
    v2f A3 = pk_mul(wx[3], xv);                                               \
    pk_fma(A0, wh[0][0], h0); pk_fma(A1, wh[1][0], h0);                       \
    pk_fma(A2, wh[2][0], h0); pk_fma(A3, wh[3][0], h0);                       \
    pk_fma(A0, wh[0][1], h1); pk_fma(A1, wh[1][1], h1);                       \
    pk_fma(A2, wh[2][1], h1); pk_fma(A3, wh[3][1], h1);                       \
    pk_fma(A0, wh[0][2], h2); pk_fma(A1, wh[1][2], h2);                       \
    pk_fma(A2, wh[2][2], h2); pk_fma(A3, wh[3][2], h2);                       \
    pk_fma(A0, wh[0][3], h3); pk_fma(A1, wh[1][3], h3);                       \
    pk_fma(A2, wh[2][3], h3); pk_fma(A3, wh[3][3], h3);                       \
    pk_fma(A0, wh[0][4], h4); pk_fma(A1, wh[1][4], h4);                       \
    pk_fma(A2, wh[2][4], h4); pk_fma(A3, wh[3][4], h4);                       \
    pk_fma(A0, wh[0][5], h5); pk_fma(A1, wh[1][5], h5);                       \
    pk_fma(A2, wh[2][5], h5); pk_fma(A3, wh[3][5], h5);                       \
    pk_fma(A0, wh[0][6], h6); pk_fma(A1, wh[1][6], h6);                       \
    pk_fma(A2, wh[2][6], h6); pk_fma(A3, wh[3][6], h6);                       \
    pk_fma(A0, wh[0][7], h7); pk_fma(A1, wh[1][7], h7);                       \
    pk_fma(A2, wh[2][7], h7); pk_fma(A3, wh[3][7], h7);                       \
    float r0 = A0.x + A0.y;                                                   \
    float r1 = A1.x + A1.y;                                                   \
    float r2 = A2.x + A2.y;                                                   \
    float r3 = A3.x + A3.y;                                                   \
    float s1 = r0 + qp_rot1(r3);                                              \
    float s2 = qp_xor2(r2) + qp_rot3(r1);                                     \
    float sum = s1 + s2;                                                      \
    float e  = __builtin_amdgcn_exp2f(sum * bk);                              \
    float rc = __builtin_amdgcn_rcpf(1.0f + e);                               \
    float a  = fmaf(bm, rc, bbc);                                             \
    float p1 = qp_xor1(a);                                                    \
    float p2 = qp_xor2(a);                                                    \
    float p3 = qp_xor2(p1);                                                   \
    c = fmaf(p1, c, a * p2);                                                  \
    float e2 = __builtin_amdgcn_exp2f(c * (-2.0f * L2E));                     \
    float rr = __builtin_amdgcn_rcpf(1.0f + e2);                              \
    float th = fmaf(2.0f, rr, -1.0f);                                         \
    *(WA) = p3 * th;                                                          \
    px += XSTR;                                                               \
    __syncthreads();                                                          \
}

    for (int k = 0; k < PRED_LEN; ++k) {
        const float* px = xq + k * XSTR;              // row k (t=0)
        for (int t = 0; t < SEQ_LEN; t += 2) {
            STEP(hp0, wa1)
            STEP(hp1, wa0)
        }
        // after 96 steps the latest h is in hb0

        // ---- prediction head: lanes 0..6 of wave 0 ----
        if (tid < FEAT) {
            float p0 = fcb[tid], p1 = 0.0f, p2 = 0.0f, p3 = 0.0f;
            const float4* hh = (const float4*)hb0;
            #pragma unroll
            for (int j = 0; j < 16; ++j) {
                float4 hv = hh[j];
                p0 = fmaf(fcw[tid * HIDDEN + 4 * j + 0], hv.x, p0);
                p1 = fmaf(fcw[tid * HIDDEN + 4 * j + 1], hv.y, p1);
                p2 = fmaf(fcw[tid * HIDDEN + 4 * j + 2], hv.z, p2);
                p3 = fmaf(fcw[tid * HIDDEN + 4 * j + 3], hv.w, p3);
            }
            float pred = (p0 + p1) + (p2 + p3);
            out[(b * PRED_LEN + k) * FEAT + tid] = pred;
            xs[(SEQ_LEN + k) * XSTR + tid] = pred;    // append; col7 stays 1.0
        }
        __syncthreads();
    }
#undef STEP
}

extern "C" void kernel_launch(void* const* d_in, const int* in_sizes, int n_in,
                              void* d_out, int out_size, void* d_ws, size_t ws_size,
                              hipStream_t stream) {
    const float* x    = (const float*)d_in[0];
    const float* W_ih = (const float*)d_in[1];
    const float* W_hh = (const float*)d_in[2];
    const float* b_ih = (const float*)d_in[3];
    const float* b_hh = (const float*)d_in[4];
    const float* fc_W = (const float*)d_in[5];
    const float* fc_b = (const float*)d_in[6];
    float* out = (float*)d_out;

    lstm_ar_kernel<<<BATCH, 256, 0, stream>>>(x, W_ih, W_hh, b_ih, b_hh, fc_W, fc_b, out);
}

// Round 8
// 572.477 us; speedup vs baseline: 1.1923x; 1.0005x over previous
//
#include <hip/hip_runtime.h>

#define SEQ_LEN 96
#define PRED_LEN 16
#define HIDDEN 64
#define FEAT 7
#define BATCH 512
#define TL (SEQ_LEN + PRED_LEN)   // 112-row sliding timeline
#define XSTR 8                    // padded row stride; col 7 == 1.0 (bias lane)

typedef float v2f __attribute__((ext_vector_type(2)));

#define L2E 1.4426950408889634f

// DPP quad ops (pure VALU). Quad = the 4 lanes of one hidden unit.
__device__ __forceinline__ float qp_xor1(float v) {  // [1,0,3,2]
    return __int_as_float(__builtin_amdgcn_mov_dpp(__float_as_int(v), 0xB1, 0xF, 0xF, true));
}
__device__ __forceinline__ float qp_xor2(float v) {  // [2,3,0,1]
    return __int_as_float(__builtin_amdgcn_mov_dpp(__float_as_int(v), 0x4E, 0xF, 0xF, true));
}
__device__ __forceinline__ float qp_rot1(float v) {  // lane q <- lane (q+1)&3 : [1,2,3,0]
    return __int_as_float(__builtin_amdgcn_mov_dpp(__float_as_int(v), 0x39, 0xF, 0xF, true));
}
__device__ __forceinline__ float qp_rot3(float v) {  // lane q <- lane (q+3)&3 : [3,0,1,2]
    return __int_as_float(__builtin_amdgcn_mov_dpp(__float_as_int(v), 0x93, 0xF, 0xF, true));
}

// Forced packed fp32 math (register-only asm, schedulable).
__device__ __forceinline__ v2f pk_mul(v2f a, v2f b) {
    v2f d;
    asm("v_pk_mul_f32 %0, %1, %2" : "=v"(d) : "v"(a), "v"(b));
    return d;
}
__device__ __forceinline__ void pk_fma(v2f& acc, v2f a, v2f b) {
    asm("v_pk_fma_f32 %0, %1, %2, %0" : "+v"(acc) : "v"(a), "v"(b));
}

// r17 = r16 + ENFORCED ANTI-PHASE between co-resident blocks.
//  Model (fits r7..r16): VALUBusy on gfx950 counts ~4cyc/wave64-inst (gfx94x
//  formula) -> real issue is only ~270 cyc/SIMD/step (no instruction fat!).
//  The wall is the SERIAL CHAIN (~850-1000 cyc: barrier->ds_read ~170,
//  FMA tail, DPP reduce w/ hazards, 4 serial transcendentals, write+drain).
//  r15 (1 block/CU) measured the chain directly: 1066 cyc/step. r13/r16's
//  two co-resident blocks overlap two ~900cyc chains to only 860/pair (~50%
//  overlap): their identical periodic step patterns phase-lock IN-phase, so
//  both waves on a SIMD stall together (the ~38% dual-stall time).
//  Fix: one-time ~450cyc s_sleep for the upper-half blocks. Round-robin
//  dispatch puts blocks i and i+256 on the same CU -> phase bit is
//  (blockIdx >> 8) & 1. Once offset, LDS-contention coupling (later block
//  slips on burst collision) should hold the anti-phase.
//  Everything else is r16, frozen.
__global__ __launch_bounds__(256)
__attribute__((amdgpu_waves_per_eu(2, 2)))
void lstm_ar_kernel(
    const float* __restrict__ x,     // [B, 96, 7]
    const float* __restrict__ W_ih,  // [256, 7]
    const float* __restrict__ W_hh,  // [256, 64]
    const float* __restrict__ b_ih,  // [256]
    const float* __restrict__ b_hh,  // [256]
    const float* __restrict__ fc_W,  // [7, 64]
    const float* __restrict__ fc_b,  // [7]
    float* __restrict__ out)         // [B, 16, 7]
{
    __shared__ float xs[TL * XSTR];   // sliding timeline, col7 = 1.0
    __shared__ float hb0[HIDDEN];     // h ping-pong
    __shared__ float hb1[HIDDEN];
    __shared__ float hscr[HIDDEN];    // garbage-h sink (never read)
    __shared__ float fcw[FEAT * HIDDEN];
    __shared__ float fcb[FEAT];

    const int tid = threadIdx.x;
    const int b   = blockIdx.x;
    const int u   = tid >> 2;         // hidden unit 0..63
    const int q   = tid & 3;          // K-quarter 0..3, also "own gate" id

    // ---- per-thread weights: 4 gates x K-quarter [16q,16q+16) ----
    // accumulator k holds gate (q+k)&3  (rotated layout for the DPP reduce)
    v2f wh[4][8];
    #pragma unroll
    for (int k = 0; k < 4; ++k) {
        const int gate = (q + k) & 3;
        const float* wr = W_hh + ((gate << 6) + u) * HIDDEN + (q << 4);
        #pragma unroll
        for (int j = 0; j < 8; ++j) wh[k][j] = *(const v2f*)(wr + 2 * j);
    }
    v2f wx[4];                        // x cols [2q, 2q+2); q==3 pairs col6 with bias
    #pragma unroll
    for (int k = 0; k < 4; ++k) {
        const int gate = (q + k) & 3;
        const int row  = (gate << 6) + u;
        const int c0 = (q << 1), c1 = c0 + 1;
        wx[k].x = W_ih[row * FEAT + c0];
        wx[k].y = (c1 < FEAT) ? W_ih[row * FEAT + c1]
                              : (b_ih[row] + b_hh[row]);   // pairs with xs col7==1.0
    }

    // ---- tuple anchors: pin each v2f weight pair in arch VGPRs, packed ----
    #pragma unroll
    for (int k = 0; k < 4; ++k) {
        #pragma unroll
        for (int j = 0; j < 8; ++j) asm volatile("" : "+v"(wh[k][j]));
        asm volatile("" : "+v"(wx[k]));
    }

    // activation constants: lane q activates gate q; gate 2 is tanh
    const float bk  = (q == 2) ? (-2.0f * L2E) : (-L2E);
    const float bm  = (q == 2) ? 2.0f : 1.0f;
    const float bbc = (q == 2) ? -1.0f : 0.0f;

    // pointers (all fixed for the whole kernel; ds offsets fold to immediates)
    const v2f* const hp0 = (const v2f*)(hb0 + (q << 4));
    const v2f* const hp1 = (const v2f*)(hb1 + (q << 4));
    float* const sink = hscr + ((u + (q << 4)) & 63);
    float* const wa1 = (q == 0) ? (hb1 + u) : sink;
    float* const wa0 = (q == 0) ? (hb0 + u) : sink;
    const float* const xq = xs + (q << 1);   // this lane's 2 x-cols

    // ---- stage timeline / fc / init ----
    for (int i = tid; i < TL * XSTR; i += 256) {
        int r = i >> 3, f = i & 7;
        float v = 1.0f;                                    // col 7 = bias input
        if (f < FEAT) v = (r < SEQ_LEN) ? x[b * SEQ_LEN * FEAT + r * FEAT + f] : 0.0f;
        xs[i] = v;
    }
    for (int i = tid; i < FEAT * HIDDEN; i += 256) fcw[i] = fc_W[i];
    if (tid < FEAT)   fcb[tid] = fc_b[tid];
    if (tid < HIDDEN) hb0[tid] = 0.0f;
    float c = 0.0f;                   // real only in q==0 lanes; bounded garbage elsewhere
    __syncthreads();

    // ---- anti-phase: upper-half blocks start ~half a step late ----
    if ((blockIdx.x >> 8) & 1) {
        __builtin_amdgcn_s_sleep(7);  // ~448 cycles, one-time
    }

// One step, fully inlined. HP = h-read base (v2f*), WA = h-write ptr.
// 9 LDS reads (1 x, 8 h) issue up front; 36 pk ops; rotation-reduce; act;
// DPP share; c/tanh; write; px advance; ONE barrier.
#define STEP(HP, WA) {                                                        \
    v2f xv = *(const v2f*)px;                                                 \
    v2f h0 = (HP)[0], h1 = (HP)[1], h2 = (HP)[2], h3 = (HP)[3];               \
    v2f h4 = (HP)[4], h5 = (HP)[5], h6 = (HP)[6], h7 = (HP)[7];               \
    v2f A0 = pk_mul(wx[0], xv);                                               \
    v2f A1 = pk_mul(wx[1], xv);                                               \
    v2f A2 = pk_mul(wx[2], xv);                                               \
    v2f A3 = pk_mul(wx[3], xv);                                               \
    pk_fma(A0, wh[0][0], h0); pk_fma(A1, wh[1][0], h0);                       \
    pk_fma(A2, wh[2][0], h0); pk_fma(A3, wh[3][0], h0);                       \
    pk_fma(A0, wh[0][1], h1); pk_fma(A1, wh[1][1], h1);                       \
    pk_fma(A2, wh[2][1], h1); pk_fma(A3, wh[3][1], h1);                       \
    pk_fma(A0, wh[0][2], h2); pk_fma(A1, wh[1][2], h2);                       \
    pk_fma(A2, wh[2][2], h2); pk_fma(A3, wh[3][2], h2);                       \
    pk_fma(A0, wh[0][3], h3); pk_fma(A1, wh[1][3], h3);                       \
    pk_fma(A2, wh[2][3], h3); pk_fma(A3, wh[3][3], h3);                       \
    pk_fma(A0, wh[0][4], h4); pk_fma(A1, wh[1][4], h4);                       \
    pk_fma(A2, wh[2][4], h4); pk_fma(A3, wh[3][4], h4);                       \
    pk_fma(A0, wh[0][5], h5); pk_fma(A1, wh[1][5], h5);                       \
    pk_fma(A2, wh[2][5], h5); pk_fma(A3, wh[3][5], h5);                       \
    pk_fma(A0, wh[0][6], h6); pk_fma(A1, wh[1][6], h6);                       \
    pk_fma(A2, wh[2][6], h6); pk_fma(A3, wh[3][6], h6);                       \
    pk_fma(A0, wh[0][7], h7); pk_fma(A1, wh[1][7], h7);                       \
    pk_fma(A2, wh[2][7], h7); pk_fma(A3, wh[3][7], h7);                       \
    float r0 = A0.x + A0.y;                                                   \
    float r1 = A1.x + A1.y;                                                   \
    float r2 = A2.x + A2.y;                                                   \
    float r3 = A3.x + A3.y;                                                   \
    float s1 = r0 + qp_rot1(r3);                                              \
    float s2 = qp_xor2(r2) + qp_rot3(r1);                                     \
    float sum = s1 + s2;                                                      \
    float e  = __builtin_amdgcn_exp2f(sum * bk);                              \
    float rc = __builtin_amdgcn_rcpf(1.0f + e);                               \
    float a  = fmaf(bm, rc, bbc);                                             \
    float p1 = qp_xor1(a);                                                    \
    float p2 = qp_xor2(a);                                                    \
    float p3 = qp_xor2(p1);                                                   \
    c = fmaf(p1, c, a * p2);                                                  \
    float e2 = __builtin_amdgcn_exp2f(c * (-2.0f * L2E));                     \
    float rr = __builtin_amdgcn_rcpf(1.0f + e2);                              \
    float th = fmaf(2.0f, rr, -1.0f);                                         \
    *(WA) = p3 * th;                                                          \
    px += XSTR;                                                               \
    __syncthreads();                                                          \
}

    for (int k = 0; k < PRED_LEN; ++k) {
        const float* px = xq + k * XSTR;              // row k (t=0)
        for (int t = 0; t < SEQ_LEN; t += 2) {
            STEP(hp0, wa1)
            STEP(hp1, wa0)
        }
        // after 96 steps the latest h is in hb0

        // ---- prediction head: lanes 0..6 of wave 0 ----
        if (tid < FEAT) {
            float p0 = fcb[tid], p1 = 0.0f, p2 = 0.0f, p3 = 0.0f;
            const float4* hh = (const float4*)hb0;
            #pragma unroll
            for (int j = 0; j < 16; ++j) {
                float4 hv = hh[j];
                p0 = fmaf(fcw[tid * HIDDEN + 4 * j + 0], hv.x, p0);
                p1 = fmaf(fcw[tid * HIDDEN + 4 * j + 1], hv.y, p1);
                p2 = fmaf(fcw[tid * HIDDEN + 4 * j + 2], hv.z, p2);
                p3 = fmaf(fcw[tid * HIDDEN + 4 * j + 3], hv.w, p3);
            }
            float pred = (p0 + p1) + (p2 + p3);
            out[(b * PRED_LEN + k) * FEAT + tid] = pred;
            xs[(SEQ_LEN + k) * XSTR + tid] = pred;    // append; col7 stays 1.0
        }
        __syncthreads();
    }
#undef STEP
}

extern "C" void kernel_launch(void* const* d_in, const int* in_sizes, int n_in,
                              void* d_out, int out_size, void* d_ws, size_t ws_size,
                              hipStream_t stream) {
    const float* x    = (const float*)d_in[0];
    const float* W_ih = (const float*)d_in[1];
    const float* W_hh = (const float*)d_in[2];
    const float* b_ih = (const float*)d_in[3];
    const float* b_hh = (const float*)d_in[4];
    const float* fc_W = (const float*)d_in[5];
    const float* fc_b = (const float*)d_in[6];
    float* out = (float*)d_out;

    lstm_ar_kernel<<<BATCH, 256, 0, stream>>>(x, W_ih, W_hh, b_ih, b_hh, fc_W, fc_b, out);
}